// Round 1
// baseline (236.848 us; speedup 1.0000x reference)
//
#include <hip/hip_runtime.h>
#include <hip/hip_bf16.h>
#include <cstdint>

// LambdaLayer on MI355X.
// b=16, dim=256, n=m=1024, HEADS=4, DIM_K=16, DIM_V=32.
// Pipeline:
//   k_convw   : w_q/w_k/w_v fp32 -> Wbf[128][256] bf16 (rows 112..127 zero)
//   k_transp  : pos_emb[n][m][k] fp32 -> Pbf[(n*16+k)][m] bf16  (GEMM A, K-contig)
//   k_proj    : per (b, px-tile 128): MFMA GEMM (128x256)@(256x128) -> q_raw/k_raw/v_raw fp32
//   k_stats   : per-channel mean/var over (b,n) -> scale/shift (96 ch)
//   k_bnq     : BN(q) + transpose -> q_bn[b][n][64] fp32
//   k_bnv     : BN(v) -> v_bn[(b*32+v)][m] bf16  (GEMM B, K-contig)
//   k_sm_lamc : softmax(k) over m + lam_c[b][16][32]
//   k_lamp    : GEMM lam_p = Pbf(16384x1024) @ v_bn^T(1024x512), +lam_c,
//               fused epilogue Y = q·lam -> out[b][h*32+v][n]

typedef __attribute__((ext_vector_type(8))) __bf16 bf16x8;
typedef __attribute__((ext_vector_type(4))) float f32x4;

__device__ __forceinline__ unsigned short f2bf(float f) {
    unsigned u = __float_as_uint(f);
    u += 0x7fffu + ((u >> 16) & 1u);   // round-to-nearest-even
    return (unsigned short)(u >> 16);
}
__device__ __forceinline__ float bf2f(unsigned short h) {
    return __uint_as_float(((unsigned)h) << 16);
}
__device__ __forceinline__ void async16(const void* g, void* l) {
    __builtin_amdgcn_global_load_lds(
        (const __attribute__((address_space(1))) void*)g,
        (__attribute__((address_space(3))) void*)l, 16, 0, 0);
}

// ---------------------------------------------------------------- k_convw
__global__ void k_convw(const float* __restrict__ wq, const float* __restrict__ wk,
                        const float* __restrict__ wv, unsigned* __restrict__ WbfU) {
    int t = blockIdx.x * 256 + threadIdx.x;   // 0..4095
#pragma unroll
    for (int r = 0; r < 4; ++r) {
        int u = r * 4096 + t;                 // 0..16383 (uint idx, 128x128)
        int row = u >> 7;                     // ch 0..127
        int cp = (u & 127) << 1;              // even c
        float f0 = 0.f, f1 = 0.f;
        if (row < 64)       { f0 = wq[row * 256 + cp];        f1 = wq[row * 256 + cp + 1]; }
        else if (row < 80)  { f0 = wk[(row - 64) * 256 + cp]; f1 = wk[(row - 64) * 256 + cp + 1]; }
        else if (row < 112) { f0 = wv[(row - 80) * 256 + cp]; f1 = wv[(row - 80) * 256 + cp + 1]; }
        WbfU[u] = (unsigned)f2bf(f0) | ((unsigned)f2bf(f1) << 16);
    }
}

// ---------------------------------------------------------------- k_transp
// Pbf[(n*16+k)][m] = pos[n][m][k]; blocked over m so L1 (32KB) holds the 16KB
// working set (each 64B line = all 16 k for one m, fetched once, used 16x).
__global__ void k_transp(const float* __restrict__ pos, unsigned* __restrict__ PbfU) {
    int n = blockIdx.x;
    int t = threadIdx.x;
    const float* src = pos + (size_t)n * 16384;
    unsigned* dst = PbfU + (size_t)n * 8192;       // 16 rows * 512 uints
#pragma unroll
    for (int mc = 0; mc < 4; ++mc) {
#pragma unroll
        for (int r = 0; r < 8; ++r) {
            int idx = r * 256 + t;                 // 0..2047
            int k = idx >> 7;                      // 0..15
            int mp = (mc << 7) + (idx & 127);      // m-pair 0..511
            float f0 = src[(mp * 2) * 16 + k];
            float f1 = src[(mp * 2 + 1) * 16 + k];
            dst[k * 512 + mp] = (unsigned)f2bf(f0) | ((unsigned)f2bf(f1) << 16);
        }
    }
}

// ---------------------------------------------------------------- k_proj
__global__ __launch_bounds__(256) void k_proj(const float* __restrict__ x,
                                              const unsigned short* __restrict__ Wbf,
                                              float* __restrict__ qraw,
                                              float* __restrict__ kraw,
                                              float* __restrict__ vraw) {
    int b = blockIdx.y;
    int px0 = blockIdx.x * 128;
    int t = threadIdx.x;
    int w = t >> 6, lane = t & 63;

    __shared__ __align__(16) unsigned short Al[128 * 32];   // swizzled, via global_load_lds
    __shared__ __align__(16) unsigned short Bl[128 * 40];   // [px][c] pad to 40 (80B rows)

    // A staging: wave w loads rows w*32..w*32+31 (two 16-row instrs)
    int srow = (w << 5) + (lane >> 2);
    int schunk = (lane & 3) ^ ((lane >> 3) & 3);
    const unsigned short* pA0 = Wbf + srow * 256 + schunk * 8;
    const unsigned short* pA1 = pA0 + 16 * 256;
    unsigned short* lA0 = &Al[w * 1024];
    unsigned short* lA1 = lA0 + 512;

    int wm = w >> 1, wn = w & 1;
    int rl = lane & 15, qq = lane >> 4;
    int sw = qq ^ ((rl >> 1) & 3);

    f32x4 acc[4][4];
#pragma unroll
    for (int i = 0; i < 4; ++i)
#pragma unroll
        for (int j = 0; j < 4; ++j)
#pragma unroll
            for (int r = 0; r < 4; ++r) acc[i][j][r] = 0.f;

    const float* xb = x + (size_t)b * 256 * 1024 + px0;

    for (int kt = 0; kt < 8; ++kt) {
        int c0 = kt * 32;
        async16(pA0 + c0, lA0);
        async16(pA1 + c0, lA1);
        // x -> Bl transposed (px-major, c contiguous), pack 2 c per dword
#pragma unroll
        for (int rep = 0; rep < 8; ++rep) {
            int idx = rep * 256 + t;
            int px = idx & 127;
            int cp = idx >> 7;                     // 0..15
            int c = c0 + cp * 2;
            float f0 = xb[(size_t)c * 1024 + px];
            float f1 = xb[(size_t)(c + 1) * 1024 + px];
            *(unsigned*)&Bl[px * 40 + cp * 2] = (unsigned)f2bf(f0) | ((unsigned)f2bf(f1) << 16);
        }
        __syncthreads();
        bf16x8 a[4], bb[4];
#pragma unroll
        for (int i = 0; i < 4; ++i) a[i]  = *(const bf16x8*)&Al[((wm << 6) + (i << 4) + rl) * 32 + sw * 8];
#pragma unroll
        for (int j = 0; j < 4; ++j) bb[j] = *(const bf16x8*)&Bl[((wn << 6) + (j << 4) + rl) * 40 + qq * 8];
#pragma unroll
        for (int i = 0; i < 4; ++i)
#pragma unroll
            for (int j = 0; j < 4; ++j)
                acc[i][j] = __builtin_amdgcn_mfma_f32_16x16x32_bf16(a[i], bb[j], acc[i][j], 0, 0, 0);
        __syncthreads();
    }

    // scatter to q/k/v (C/D layout: col=lane&15 (px), row=(lane>>4)*4+r (ch))
#pragma unroll
    for (int i = 0; i < 4; ++i) {
#pragma unroll
        for (int j = 0; j < 4; ++j) {
            int px = px0 + (wn << 6) + (j << 4) + (lane & 15);
#pragma unroll
            for (int r = 0; r < 4; ++r) {
                int ch = (wm << 6) + (i << 4) + ((lane >> 4) << 2) + r;
                float val = acc[i][j][r];
                if (ch < 64)       qraw[((size_t)b * 64 + ch) * 1024 + px] = val;
                else if (ch < 80)  kraw[((size_t)b * 16 + (ch - 64)) * 1024 + px] = val;
                else if (ch < 112) vraw[((size_t)b * 32 + (ch - 80)) * 1024 + px] = val;
            }
        }
    }
}

// ---------------------------------------------------------------- k_stats
__global__ void k_stats(const float* __restrict__ qraw, const float* __restrict__ vraw,
                        const float* __restrict__ gq, const float* __restrict__ bq,
                        const float* __restrict__ gv, const float* __restrict__ bv,
                        float* __restrict__ scaleArr, float* __restrict__ shiftArr) {
    int ch = blockIdx.x;   // 0..95 (0..63 q, 64..95 v)
    int t = threadIdx.x;
    const float* base;
    size_t bstride;
    if (ch < 64) { base = qraw + (size_t)ch * 1024; bstride = 64 * 1024; }
    else         { base = vraw + (size_t)(ch - 64) * 1024; bstride = 32 * 1024; }
    float s = 0.f, ss = 0.f;
    for (int b = 0; b < 16; ++b) {
        const float* p = base + b * bstride;
#pragma unroll
        for (int i = 0; i < 4; ++i) { float v = p[t + i * 256]; s += v; ss += v * v; }
    }
#pragma unroll
    for (int off = 32; off; off >>= 1) { s += __shfl_down(s, off); ss += __shfl_down(ss, off); }
    __shared__ float rs[4], rss[4];
    if ((t & 63) == 0) { rs[t >> 6] = s; rss[t >> 6] = ss; }
    __syncthreads();
    if (t == 0) {
        s = rs[0] + rs[1] + rs[2] + rs[3];
        ss = rss[0] + rss[1] + rss[2] + rss[3];
        float mean = s * (1.f / 16384.f);
        float var = ss * (1.f / 16384.f) - mean * mean;   // biased, matches jnp.var
        float g, be;
        if (ch < 64) { g = gq[ch]; be = bq[ch]; } else { g = gv[ch - 64]; be = bv[ch - 64]; }
        float sc = g * rsqrtf(var + 1e-5f);
        scaleArr[ch] = sc;
        shiftArr[ch] = be - mean * sc;
    }
}

// ---------------------------------------------------------------- k_bnq
__global__ void k_bnq(const float* __restrict__ qraw, const float* __restrict__ scaleArr,
                      const float* __restrict__ shiftArr, float* __restrict__ qbn) {
    int nt = blockIdx.x, b = blockIdx.y;
    int t = threadIdx.x;
    __shared__ float Q[64 * 65];
    const float* src = qraw + (size_t)b * 64 * 1024 + nt * 64;
#pragma unroll
    for (int r = 0; r < 16; ++r) {
        int idx = r * 256 + t; int ch = idx >> 6; int nl = idx & 63;
        Q[ch * 65 + nl] = src[(size_t)ch * 1024 + nl];
    }
    __syncthreads();
    float* dst = qbn + ((size_t)b * 1024 + nt * 64) * 64;
#pragma unroll
    for (int r = 0; r < 16; ++r) {
        int idx = r * 256 + t; int nl = idx >> 6; int ch = idx & 63;
        dst[(size_t)nl * 64 + ch] = Q[ch * 65 + nl] * scaleArr[ch] + shiftArr[ch];
    }
}

// ---------------------------------------------------------------- k_bnv
__global__ void k_bnv(const float* __restrict__ vraw, const float* __restrict__ scaleArr,
                      const float* __restrict__ shiftArr, unsigned* __restrict__ vbnU) {
    int t = blockIdx.x * 256 + threadIdx.x;   // 65536 threads
#pragma unroll
    for (int r = 0; r < 4; ++r) {
        int u = r * 65536 + t;                // uint idx 0..262143
        int row = u >> 9;                     // (b*32+v)
        int vch = row & 31;
        float sc = scaleArr[64 + vch], sh = shiftArr[64 + vch];
        float f0 = vraw[2 * u] * sc + sh;
        float f1 = vraw[2 * u + 1] * sc + sh;
        vbnU[u] = (unsigned)f2bf(f0) | ((unsigned)f2bf(f1) << 16);
    }
}

// ---------------------------------------------------------------- k_sm_lamc
__global__ void k_sm_lamc(const float* __restrict__ kraw, const unsigned short* __restrict__ vbn,
                          float* __restrict__ lamc) {
    int kch = blockIdx.x, b = blockIdx.y;
    int t = threadIdx.x; int w = t >> 6; int lane = t & 63;
    const float* kr = kraw + ((size_t)b * 16 + kch) * 1024;
    float xv[4];
    float mx = -1e30f;
#pragma unroll
    for (int i = 0; i < 4; ++i) { xv[i] = kr[t + i * 256]; mx = fmaxf(mx, xv[i]); }
#pragma unroll
    for (int off = 32; off; off >>= 1) mx = fmaxf(mx, __shfl_down(mx, off));
    __shared__ float red[4];
    __shared__ float pr[4][32];
    if (lane == 0) red[w] = mx;
    __syncthreads();
    mx = fmaxf(fmaxf(red[0], red[1]), fmaxf(red[2], red[3]));
    float e[4]; float s = 0.f;
#pragma unroll
    for (int i = 0; i < 4; ++i) { e[i] = __expf(xv[i] - mx); s += e[i]; }
#pragma unroll
    for (int off = 32; off; off >>= 1) s += __shfl_down(s, off);
    __syncthreads();
    if (lane == 0) red[w] = s;
    __syncthreads();
    float inv = 1.f / (red[0] + red[1] + red[2] + red[3]);
    const unsigned short* vb = vbn + (size_t)b * 32 * 1024;
    for (int vch = 0; vch < 32; ++vch) {
        const unsigned short* vr = vb + (size_t)vch * 1024;
        float p = 0.f;
#pragma unroll
        for (int i = 0; i < 4; ++i) p += e[i] * bf2f(vr[t + i * 256]);
#pragma unroll
        for (int off = 32; off; off >>= 1) p += __shfl_down(p, off);
        if (lane == 0) pr[w][vch] = p;
    }
    __syncthreads();
    if (t < 32) {
        float tot = pr[0][t] + pr[1][t] + pr[2][t] + pr[3][t];
        lamc[((size_t)b * 16 + kch) * 32 + t] = inv * tot;
    }
}

// ---------------------------------------------------------------- k_lamp
// C rows = n*16+kk (M=16384), cols = b*32+v (N=512), K = m (1024).
__global__ __launch_bounds__(256) void k_lamp(const unsigned short* __restrict__ Pbf,
                                              const unsigned short* __restrict__ vbn,
                                              const float* __restrict__ qbn,
                                              const float* __restrict__ lamc,
                                              float* __restrict__ out) {
    int ntile = blockIdx.x;    // 0..3   (cols: 4 batches x 32 v)
    int mtile = blockIdx.y;    // 0..127 (rows: 8 n x 16 k)
    int t = threadIdx.x;
    int w = t >> 6, lane = t & 63;

    __shared__ union {
        struct { __align__(16) unsigned short A[128 * 32]; __align__(16) unsigned short B[128 * 32]; } st;
        float Y[128 * 128];
    } sm;

    int srow = (w << 5) + (lane >> 2);
    int schunk = (lane & 3) ^ ((lane >> 3) & 3);
    const unsigned short* pA = Pbf + ((size_t)(mtile * 128) + srow) * 1024 + schunk * 8;
    const unsigned short* pB = vbn + ((size_t)(ntile * 128) + srow) * 1024 + schunk * 8;
    unsigned short* lA0 = &sm.st.A[w * 1024];
    unsigned short* lA1 = lA0 + 512;
    unsigned short* lB0 = &sm.st.B[w * 1024];
    unsigned short* lB1 = lB0 + 512;

    int wm = w >> 1, wn = w & 1;
    int rl = lane & 15, qq = lane >> 4;
    int swz = qq ^ ((rl >> 1) & 3);
    int aoff[4], boff[4];
#pragma unroll
    for (int i = 0; i < 4; ++i) aoff[i] = ((wm << 6) + (i << 4) + rl) * 32 + swz * 8;
#pragma unroll
    for (int j = 0; j < 4; ++j) boff[j] = ((wn << 6) + (j << 4) + rl) * 32 + swz * 8;

    f32x4 acc[4][4];
#pragma unroll
    for (int i = 0; i < 4; ++i)
#pragma unroll
        for (int j = 0; j < 4; ++j)
#pragma unroll
            for (int r = 0; r < 4; ++r) acc[i][j][r] = 0.f;

    for (int kt = 0; kt < 32; ++kt) {
        int m0 = kt * 32;
        async16(pA + m0, lA0);
        async16(pA + 16 * 1024 + m0, lA1);
        async16(pB + m0, lB0);
        async16(pB + 16 * 1024 + m0, lB1);
        __syncthreads();
        bf16x8 a[4], bb[4];
#pragma unroll
        for (int i = 0; i < 4; ++i) a[i]  = *(const bf16x8*)&sm.st.A[aoff[i]];
#pragma unroll
        for (int j = 0; j < 4; ++j) bb[j] = *(const bf16x8*)&sm.st.B[boff[j]];
#pragma unroll
        for (int i = 0; i < 4; ++i)
#pragma unroll
            for (int j = 0; j < 4; ++j)
                acc[i][j] = __builtin_amdgcn_mfma_f32_16x16x32_bf16(a[i], bb[j], acc[i][j], 0, 0, 0);
        __syncthreads();
    }

    // acc + lam_c -> LDS (reuses the staging LDS; all frag reads drained by last barrier)
    int b0 = ntile * 4;
#pragma unroll
    for (int i = 0; i < 4; ++i) {
        int row_b = (wm << 6) + (i << 4) + ((lane >> 4) << 2);
#pragma unroll
        for (int j = 0; j < 4; ++j) {
            int col = (wn << 6) + (j << 4) + (lane & 15);
            int bcol = col >> 5, vv = col & 31;
            const float* lc = lamc + ((size_t)(b0 + bcol) * 16) * 32 + vv;
#pragma unroll
            for (int r = 0; r < 4; ++r) {
                int row = row_b + r;
                sm.Y[row * 128 + col] = acc[i][j][r] + lc[(row & 15) * 32];
            }
        }
    }
    __syncthreads();

    // Epilogue: thread owns (b, h, v0..v0+1), loops 8 n: Y_out = sum_k q * lam
    int c0 = t * 2;
    int bb2 = c0 >> 7;
    int hh = (c0 >> 5) & 3;
    int v0 = c0 & 31;                  // even
    int bglob = b0 + bb2;
    float o0[8], o1[8];
#pragma unroll
    for (int nn = 0; nn < 8; ++nn) { o0[nn] = 0.f; o1[nn] = 0.f; }
    const float* qb = qbn + ((size_t)bglob * 1024 + mtile * 8) * 64 + hh * 16;
#pragma unroll
    for (int nn = 0; nn < 8; ++nn) {
        const float* qr = qb + nn * 64;
        float qv[16];
        *(float4*)&qv[0]  = *(const float4*)&qr[0];
        *(float4*)&qv[4]  = *(const float4*)&qr[4];
        *(float4*)&qv[8]  = *(const float4*)&qr[8];
        *(float4*)&qv[12] = *(const float4*)&qr[12];
        const float* yrow = &sm.Y[(nn * 16) * 128 + bb2 * 32 + v0];
#pragma unroll
        for (int k = 0; k < 16; ++k) {
            float y0 = yrow[k * 128];
            float y1 = yrow[k * 128 + 1];
            o0[nn] += qv[k] * y0;
            o1[nn] += qv[k] * y1;
        }
    }
    float* op = out + ((size_t)bglob * 128 + hh * 32 + v0) * 1024 + mtile * 8;
    ((float4*)op)[0] = make_float4(o0[0], o0[1], o0[2], o0[3]);
    ((float4*)op)[1] = make_float4(o0[4], o0[5], o0[6], o0[7]);
    float* op1 = op + 1024;
    ((float4*)op1)[0] = make_float4(o1[0], o1[1], o1[2], o1[3]);
    ((float4*)op1)[1] = make_float4(o1[4], o1[5], o1[6], o1[7]);
}

// ---------------------------------------------------------------- launch
extern "C" void kernel_launch(void* const* d_in, const int* in_sizes, int n_in,
                              void* d_out, int out_size, void* d_ws, size_t ws_size,
                              hipStream_t stream) {
    const float* x   = (const float*)d_in[0];
    const float* wq  = (const float*)d_in[1];
    const float* wk  = (const float*)d_in[2];
    const float* wv  = (const float*)d_in[3];
    const float* pos = (const float*)d_in[4];
    const float* gq  = (const float*)d_in[5];
    const float* bq  = (const float*)d_in[6];
    const float* gv  = (const float*)d_in[7];
    const float* bv  = (const float*)d_in[8];
    float* out = (float*)d_out;

    char* ws = (char*)d_ws;
    unsigned short* Pbf  = (unsigned short*)(ws);              // 33554432 B
    unsigned short* Wbf  = (unsigned short*)(ws + 33554432);   //    65536 B
    float* qraw          = (float*)(ws + 33619968);            //  4194304 B
    float* kraw          = (float*)(ws + 37814272);            //  1048576 B
    float* vraw          = (float*)(ws + 38862848);            //  2097152 B
    float* qbn           = (float*)(ws + 40960000);            //  4194304 B
    unsigned short* vbn  = (unsigned short*)(ws + 45154304);   //  1048576 B
    float* scaleArr      = (float*)(ws + 46202880);            //      512 B
    float* shiftArr      = (float*)(ws + 46203392);            //      512 B
    float* lamc          = (float*)(ws + 46203904);            //    32768 B
    // total ~46.2 MB of workspace

    k_convw<<<dim3(16), dim3(256), 0, stream>>>(wq, wk, wv, (unsigned*)Wbf);
    k_transp<<<dim3(1024), dim3(256), 0, stream>>>(pos, (unsigned*)Pbf);
    k_proj<<<dim3(8, 16), dim3(256), 0, stream>>>(x, Wbf, qraw, kraw, vraw);
    k_stats<<<dim3(96), dim3(256), 0, stream>>>(qraw, vraw, gq, bq, gv, bv, scaleArr, shiftArr);
    k_bnq<<<dim3(16, 16), dim3(256), 0, stream>>>(qraw, scaleArr, shiftArr, qbn);
    k_bnv<<<dim3(256), dim3(256), 0, stream>>>(vraw, scaleArr, shiftArr, (unsigned*)vbn);
    k_sm_lamc<<<dim3(16, 16), dim3(256), 0, stream>>>(kraw, vbn, lamc);
    k_lamp<<<dim3(4, 128), dim3(256), 0, stream>>>(Pbf, vbn, qbn, lamc, out);
}

// Round 2
// 198.442 us; speedup vs baseline: 1.1935x; 1.1935x over previous
//
#include <hip/hip_runtime.h>
#include <hip/hip_bf16.h>
#include <cstdint>

// LambdaLayer on MI355X. b=16, dim=256, n=m=1024, HEADS=4, DIM_K=16, DIM_V=32.
// Pipeline (6 launches):
//   k_transp  : pos[n][m][k] fp32 -> Pbf[(n*16+k)][m] bf16 (LDS transpose, coalesced)
//               + blocks 1024..1039: w_q/w_k/w_v -> Wbf[128][256] bf16
//   k_proj    : per (b, px-tile 128): MFMA GEMM -> q_raw/k_raw/v_raw fp32
//   k_stats   : per-channel mean/var over (b,n) -> scale/shift (96 ch)
//   k_bn      : BN(q)+transpose -> qbn[b][n][64] fp32 ; BN(v) -> vbn[(b*32+v)][m] bf16
//   k_sm_lamc : softmax(k) over m + lam_c[b][16][32]
//   k_lamp    : GEMM lam_p = Pbf(16384x1024) @ vbn^T(1024x512), double-buffered
//               BK=64 staging via global_load_lds, +lam_c, fused epilogue Y=q*lam

typedef __attribute__((ext_vector_type(8))) __bf16 bf16x8;
typedef __attribute__((ext_vector_type(4))) float f32x4;

__device__ __forceinline__ unsigned short f2bf(float f) {
    unsigned u = __float_as_uint(f);
    u += 0x7fffu + ((u >> 16) & 1u);   // round-to-nearest-even
    return (unsigned short)(u >> 16);
}
__device__ __forceinline__ float bf2f(unsigned short h) {
    return __uint_as_float(((unsigned)h) << 16);
}
__device__ __forceinline__ void async16(const void* g, void* l) {
    __builtin_amdgcn_global_load_lds(
        (const __attribute__((address_space(1))) void*)g,
        (__attribute__((address_space(3))) void*)l, 16, 0, 0);
}

// ---------------------------------------------------------------- k_transp (+convw)
// blocks 0..1023: one n each. Phase1: coalesced float4 read -> bf16 -> LDS[k][m]
// (pad 1032 so phase-2 b64 reads are 2-way/free). Phase2: uint2 coalesced writes.
__global__ __launch_bounds__(256) void k_transp(const float* __restrict__ pos,
                                                unsigned* __restrict__ PbfU,
                                                const float* __restrict__ wq,
                                                const float* __restrict__ wk,
                                                const float* __restrict__ wv,
                                                unsigned* __restrict__ WbfU) {
    int blk = blockIdx.x;
    int t = threadIdx.x;
    if (blk >= 1024) {                    // weight conversion (16 blocks)
        int tt = (blk - 1024) * 256 + t;  // 0..4095
#pragma unroll
        for (int r = 0; r < 4; ++r) {
            int u = r * 4096 + tt;        // uint idx, 128x128
            int row = u >> 7;
            int cp = (u & 127) << 1;
            float f0 = 0.f, f1 = 0.f;
            if (row < 64)       { f0 = wq[row * 256 + cp];        f1 = wq[row * 256 + cp + 1]; }
            else if (row < 80)  { f0 = wk[(row - 64) * 256 + cp]; f1 = wk[(row - 64) * 256 + cp + 1]; }
            else if (row < 112) { f0 = wv[(row - 80) * 256 + cp]; f1 = wv[(row - 80) * 256 + cp + 1]; }
            WbfU[u] = (unsigned)f2bf(f0) | ((unsigned)f2bf(f1) << 16);
        }
        return;
    }
    __shared__ __align__(16) unsigned short L[16 * 1032];
    const float4* src = (const float4*)(pos + (size_t)blk * 16384);
#pragma unroll
    for (int r = 0; r < 16; ++r) {
        int idx4 = r * 256 + t;           // 0..4095 float4s
        float4 f = src[idx4];
        int m = idx4 >> 2, k0 = (idx4 & 3) << 2;
        L[(k0 + 0) * 1032 + m] = f2bf(f.x);
        L[(k0 + 1) * 1032 + m] = f2bf(f.y);
        L[(k0 + 2) * 1032 + m] = f2bf(f.z);
        L[(k0 + 3) * 1032 + m] = f2bf(f.w);
    }
    __syncthreads();
    uint2* dst = (uint2*)(PbfU + (size_t)blk * 8192);
#pragma unroll
    for (int r = 0; r < 16; ++r) {
        int c = r * 256 + t;              // uint2 chunk 0..4095
        int k = c >> 8, mo = c & 255;     // m0 = mo*4
        dst[c] = *(const uint2*)&L[k * 1032 + mo * 4];
    }
}

// ---------------------------------------------------------------- k_proj
__global__ __launch_bounds__(256) void k_proj(const float* __restrict__ x,
                                              const unsigned short* __restrict__ Wbf,
                                              float* __restrict__ qraw,
                                              float* __restrict__ kraw,
                                              float* __restrict__ vraw) {
    int b = blockIdx.y;
    int px0 = blockIdx.x * 128;
    int t = threadIdx.x;
    int w = t >> 6, lane = t & 63;

    __shared__ __align__(16) unsigned short Al[128 * 32];
    __shared__ __align__(16) unsigned short Bl[128 * 40];

    int srow = (w << 5) + (lane >> 2);
    int schunk = (lane & 3) ^ ((lane >> 3) & 3);
    const unsigned short* pA0 = Wbf + srow * 256 + schunk * 8;
    const unsigned short* pA1 = pA0 + 16 * 256;
    unsigned short* lA0 = &Al[w * 1024];
    unsigned short* lA1 = lA0 + 512;

    int wm = w >> 1, wn = w & 1;
    int rl = lane & 15, qq = lane >> 4;
    int sw = qq ^ ((rl >> 1) & 3);

    f32x4 acc[4][4];
#pragma unroll
    for (int i = 0; i < 4; ++i)
#pragma unroll
        for (int j = 0; j < 4; ++j)
#pragma unroll
            for (int r = 0; r < 4; ++r) acc[i][j][r] = 0.f;

    const float* xb = x + (size_t)b * 256 * 1024 + px0;

    for (int kt = 0; kt < 8; ++kt) {
        int c0 = kt * 32;
        async16(pA0 + c0, lA0);
        async16(pA1 + c0, lA1);
#pragma unroll
        for (int rep = 0; rep < 8; ++rep) {
            int idx = rep * 256 + t;
            int px = idx & 127;
            int cp = idx >> 7;
            int c = c0 + cp * 2;
            float f0 = xb[(size_t)c * 1024 + px];
            float f1 = xb[(size_t)(c + 1) * 1024 + px];
            *(unsigned*)&Bl[px * 40 + cp * 2] = (unsigned)f2bf(f0) | ((unsigned)f2bf(f1) << 16);
        }
        __syncthreads();
        bf16x8 a[4], bb[4];
#pragma unroll
        for (int i = 0; i < 4; ++i) a[i]  = *(const bf16x8*)&Al[((wm << 6) + (i << 4) + rl) * 32 + sw * 8];
#pragma unroll
        for (int j = 0; j < 4; ++j) bb[j] = *(const bf16x8*)&Bl[((wn << 6) + (j << 4) + rl) * 40 + qq * 8];
#pragma unroll
        for (int i = 0; i < 4; ++i)
#pragma unroll
            for (int j = 0; j < 4; ++j)
                acc[i][j] = __builtin_amdgcn_mfma_f32_16x16x32_bf16(a[i], bb[j], acc[i][j], 0, 0, 0);
        __syncthreads();
    }

#pragma unroll
    for (int i = 0; i < 4; ++i) {
#pragma unroll
        for (int j = 0; j < 4; ++j) {
            int px = px0 + (wn << 6) + (j << 4) + (lane & 15);
#pragma unroll
            for (int r = 0; r < 4; ++r) {
                int ch = (wm << 6) + (i << 4) + ((lane >> 4) << 2) + r;
                float val = acc[i][j][r];
                if (ch < 64)       qraw[((size_t)b * 64 + ch) * 1024 + px] = val;
                else if (ch < 80)  kraw[((size_t)b * 16 + (ch - 64)) * 1024 + px] = val;
                else if (ch < 112) vraw[((size_t)b * 32 + (ch - 80)) * 1024 + px] = val;
            }
        }
    }
}

// ---------------------------------------------------------------- k_stats
__global__ __launch_bounds__(1024) void k_stats(const float* __restrict__ qraw,
                                                const float* __restrict__ vraw,
                                                const float* __restrict__ gq, const float* __restrict__ bq,
                                                const float* __restrict__ gv, const float* __restrict__ bv,
                                                float* __restrict__ scaleArr, float* __restrict__ shiftArr) {
    int ch = blockIdx.x;   // 0..95
    int t = threadIdx.x;   // 0..1023
    const float* base;
    size_t bstride;
    if (ch < 64) { base = qraw + (size_t)ch * 1024; bstride = 64 * 1024; }
    else         { base = vraw + (size_t)(ch - 64) * 1024; bstride = 32 * 1024; }
    float s = 0.f, ss = 0.f;
#pragma unroll
    for (int b = 0; b < 16; ++b) { float v = base[b * bstride + t]; s += v; ss += v * v; }
#pragma unroll
    for (int off = 32; off; off >>= 1) { s += __shfl_down(s, off); ss += __shfl_down(ss, off); }
    __shared__ float rs[16], rss[16];
    if ((t & 63) == 0) { rs[t >> 6] = s; rss[t >> 6] = ss; }
    __syncthreads();
    if (t == 0) {
        s = 0.f; ss = 0.f;
#pragma unroll
        for (int i = 0; i < 16; ++i) { s += rs[i]; ss += rss[i]; }
        float mean = s * (1.f / 16384.f);
        float var = ss * (1.f / 16384.f) - mean * mean;
        float g, be;
        if (ch < 64) { g = gq[ch]; be = bq[ch]; } else { g = gv[ch - 64]; be = bv[ch - 64]; }
        float sc = g * rsqrtf(var + 1e-5f);
        scaleArr[ch] = sc;
        shiftArr[ch] = be - mean * sc;
    }
}

// ---------------------------------------------------------------- k_bn (bnq + bnv merged)
__global__ void k_bn(const float* __restrict__ qraw, const float* __restrict__ vraw,
                     const float* __restrict__ scaleArr, const float* __restrict__ shiftArr,
                     float* __restrict__ qbn, unsigned* __restrict__ vbnU) {
    int bx = blockIdx.x;
    int t = threadIdx.x;
    if (bx < 256) {   // BN(q) + transpose
        int nt = bx & 15, b = bx >> 4;
        __shared__ float Q[64 * 65];
        const float* src = qraw + (size_t)b * 64 * 1024 + nt * 64;
#pragma unroll
        for (int r = 0; r < 16; ++r) {
            int idx = r * 256 + t; int ch = idx >> 6; int nl = idx & 63;
            Q[ch * 65 + nl] = src[(size_t)ch * 1024 + nl];
        }
        __syncthreads();
        float* dst = qbn + ((size_t)b * 1024 + nt * 64) * 64;
#pragma unroll
        for (int r = 0; r < 16; ++r) {
            int idx = r * 256 + t; int nl = idx >> 6; int ch = idx & 63;
            dst[(size_t)nl * 64 + ch] = Q[ch * 65 + nl] * scaleArr[ch] + shiftArr[ch];
        }
    } else {          // BN(v) -> bf16
        int tt = (bx - 256) * 256 + t;
#pragma unroll
        for (int r = 0; r < 4; ++r) {
            int u = r * 65536 + tt;           // uint idx 0..262143
            int row = u >> 9;
            int vch = row & 31;
            float sc = scaleArr[64 + vch], sh = shiftArr[64 + vch];
            float f0 = vraw[2 * u] * sc + sh;
            float f1 = vraw[2 * u + 1] * sc + sh;
            vbnU[u] = (unsigned)f2bf(f0) | ((unsigned)f2bf(f1) << 16);
        }
    }
}

// ---------------------------------------------------------------- k_sm_lamc
__global__ void k_sm_lamc(const float* __restrict__ kraw, const unsigned short* __restrict__ vbn,
                          float* __restrict__ lamc) {
    int kch = blockIdx.x, b = blockIdx.y;
    int t = threadIdx.x; int w = t >> 6; int lane = t & 63;
    const float* kr = kraw + ((size_t)b * 16 + kch) * 1024;
    float xv[4];
    float mx = -1e30f;
#pragma unroll
    for (int i = 0; i < 4; ++i) { xv[i] = kr[t + i * 256]; mx = fmaxf(mx, xv[i]); }
#pragma unroll
    for (int off = 32; off; off >>= 1) mx = fmaxf(mx, __shfl_down(mx, off));
    __shared__ float red[4];
    __shared__ float pr[4][32];
    if (lane == 0) red[w] = mx;
    __syncthreads();
    mx = fmaxf(fmaxf(red[0], red[1]), fmaxf(red[2], red[3]));
    float e[4]; float s = 0.f;
#pragma unroll
    for (int i = 0; i < 4; ++i) { e[i] = __expf(xv[i] - mx); s += e[i]; }
#pragma unroll
    for (int off = 32; off; off >>= 1) s += __shfl_down(s, off);
    __syncthreads();
    if (lane == 0) red[w] = s;
    __syncthreads();
    float inv = 1.f / (red[0] + red[1] + red[2] + red[3]);
    const unsigned short* vb = vbn + (size_t)b * 32 * 1024;
    for (int vch = 0; vch < 32; ++vch) {
        const unsigned short* vr = vb + (size_t)vch * 1024;
        float p = 0.f;
#pragma unroll
        for (int i = 0; i < 4; ++i) p += e[i] * bf2f(vr[t + i * 256]);
#pragma unroll
        for (int off = 32; off; off >>= 1) p += __shfl_down(p, off);
        if (lane == 0) pr[w][vch] = p;
    }
    __syncthreads();
    if (t < 32) {
        float tot = pr[0][t] + pr[1][t] + pr[2][t] + pr[3][t];
        lamc[((size_t)b * 16 + kch) * 32 + t] = inv * tot;
    }
}

// ---------------------------------------------------------------- k_lamp
// GEMM: M=16384 (rows n*16+kk), N=512 (cols b*32+v), K=1024 (m).
// grid(128,4): x=mtile so the 4 ntile siblings share id%8 -> same XCD L2.
// BK=64, double-buffered staging: prefetch kt+1 issued before compute(kt).
__global__ __launch_bounds__(256) void k_lamp(const unsigned short* __restrict__ Pbf,
                                              const unsigned short* __restrict__ vbn,
                                              const float* __restrict__ qbn,
                                              const float* __restrict__ lamc,
                                              float* __restrict__ out) {
    int mtile = blockIdx.x;    // 0..127
    int ntile = blockIdx.y;    // 0..3
    int t = threadIdx.x;
    int w = t >> 6, lane = t & 63;

    __shared__ union {
        __align__(16) unsigned short st[4][8192];   // A0,B0,A1,B1 (16KB each)
        float Y[128 * 128];
    } sm;

    // staging: wave w covers rows w*32..w*32+31; 4 async16 per matrix per buffer.
    // LDS A layout: [row][8 octets of 8 shorts], octet XOR-swizzled by row&7.
    int roff = lane >> 3;                       // row within 8-row group
    int jx = (lane & 7) ^ (roff & 7);           // source octet for this lane
    const unsigned short* pA[4];
    const unsigned short* pB[4];
#pragma unroll
    for (int i = 0; i < 4; ++i) {
        int rowA = mtile * 128 + w * 32 + i * 8 + roff;
        int rowB = ntile * 128 + w * 32 + i * 8 + roff;
        pA[i] = Pbf + (size_t)rowA * 1024 + jx * 8;
        pB[i] = vbn + (size_t)rowB * 1024 + jx * 8;
    }

    int wm = w >> 1, wn = w & 1;
    int rl = lane & 15, qq = lane >> 4;
    int aoff[2][4], boff[2][4];
#pragma unroll
    for (int ks = 0; ks < 2; ++ks)
#pragma unroll
        for (int i = 0; i < 4; ++i) {
            int rowA = wm * 64 + i * 16 + rl;
            aoff[ks][i] = rowA * 64 + (((ks * 4 + qq) ^ (rowA & 7)) << 3);
            int rowB = wn * 64 + i * 16 + rl;
            boff[ks][i] = rowB * 64 + (((ks * 4 + qq) ^ (rowB & 7)) << 3);
        }

    f32x4 acc[4][4];
#pragma unroll
    for (int i = 0; i < 4; ++i)
#pragma unroll
        for (int j = 0; j < 4; ++j)
#pragma unroll
            for (int r = 0; r < 4; ++r) acc[i][j][r] = 0.f;

    auto stage = [&](unsigned short* dstA, int kk) {
        unsigned short* dstB = dstA + 8192;
#pragma unroll
        for (int i = 0; i < 4; ++i) {
            async16(pA[i] + kk * 64, dstA + w * 2048 + i * 512);
            async16(pB[i] + kk * 64, dstB + w * 2048 + i * 512);
        }
    };

    stage(sm.st[0], 0);
    __syncthreads();

    for (int kt = 0; kt < 16; ++kt) {
        unsigned short* curA = sm.st[(kt & 1) ? 2 : 0];
        unsigned short* curB = curA + 8192;
        if (kt < 15) stage(sm.st[(kt & 1) ? 0 : 2], kt + 1);
#pragma unroll
        for (int ks = 0; ks < 2; ++ks) {
            bf16x8 a[4], bb[4];
#pragma unroll
            for (int i = 0; i < 4; ++i) a[i]  = *(const bf16x8*)&curA[aoff[ks][i]];
#pragma unroll
            for (int j = 0; j < 4; ++j) bb[j] = *(const bf16x8*)&curB[boff[ks][j]];
#pragma unroll
            for (int i = 0; i < 4; ++i)
#pragma unroll
                for (int j = 0; j < 4; ++j)
                    acc[i][j] = __builtin_amdgcn_mfma_f32_16x16x32_bf16(a[i], bb[j], acc[i][j], 0, 0, 0);
        }
        __syncthreads();
    }

    // acc + lam_c -> LDS Y
    int b0 = ntile * 4;
#pragma unroll
    for (int i = 0; i < 4; ++i) {
        int row_b = (wm << 6) + (i << 4) + ((lane >> 4) << 2);
#pragma unroll
        for (int j = 0; j < 4; ++j) {
            int col = (wn << 6) + (j << 4) + (lane & 15);
            int bcol = col >> 5, vv = col & 31;
            const float* lc = lamc + ((size_t)(b0 + bcol) * 16) * 32 + vv;
#pragma unroll
            for (int r = 0; r < 4; ++r) {
                int row = row_b + r;
                sm.Y[row * 128 + col] = acc[i][j][r] + lc[(row & 15) * 32];
            }
        }
    }
    __syncthreads();

    // epilogue: thread owns (b, h, v0..v0+1), loops 8 n: out = sum_k q * lam
    int c0 = t * 2;
    int bb2 = c0 >> 7;
    int hh = (c0 >> 5) & 3;
    int v0 = c0 & 31;
    int bglob = b0 + bb2;
    float o0[8], o1[8];
#pragma unroll
    for (int nn = 0; nn < 8; ++nn) { o0[nn] = 0.f; o1[nn] = 0.f; }
    const float* qb = qbn + ((size_t)bglob * 1024 + mtile * 8) * 64 + hh * 16;
#pragma unroll
    for (int nn = 0; nn < 8; ++nn) {
        const float* qr = qb + nn * 64;
        float qv[16];
        *(float4*)&qv[0]  = *(const float4*)&qr[0];
        *(float4*)&qv[4]  = *(const float4*)&qr[4];
        *(float4*)&qv[8]  = *(const float4*)&qr[8];
        *(float4*)&qv[12] = *(const float4*)&qr[12];
        const float* yrow = &sm.Y[(nn * 16) * 128 + bb2 * 32 + v0];
#pragma unroll
        for (int k = 0; k < 16; ++k) {
            float y0 = yrow[k * 128];
            float y1 = yrow[k * 128 + 1];
            o0[nn] += qv[k] * y0;
            o1[nn] += qv[k] * y1;
        }
    }
    float* op = out + ((size_t)bglob * 128 + hh * 32 + v0) * 1024 + mtile * 8;
    ((float4*)op)[0] = make_float4(o0[0], o0[1], o0[2], o0[3]);
    ((float4*)op)[1] = make_float4(o0[4], o0[5], o0[6], o0[7]);
    float* op1 = op + 1024;
    ((float4*)op1)[0] = make_float4(o1[0], o1[1], o1[2], o1[3]);
    ((float4*)op1)[1] = make_float4(o1[4], o1[5], o1[6], o1[7]);
}

// ---------------------------------------------------------------- launch
extern "C" void kernel_launch(void* const* d_in, const int* in_sizes, int n_in,
                              void* d_out, int out_size, void* d_ws, size_t ws_size,
                              hipStream_t stream) {
    const float* x   = (const float*)d_in[0];
    const float* wq  = (const float*)d_in[1];
    const float* wk  = (const float*)d_in[2];
    const float* wv  = (const float*)d_in[3];
    const float* pos = (const float*)d_in[4];
    const float* gq  = (const float*)d_in[5];
    const float* bq  = (const float*)d_in[6];
    const float* gv  = (const float*)d_in[7];
    const float* bv  = (const float*)d_in[8];
    float* out = (float*)d_out;

    char* ws = (char*)d_ws;
    unsigned short* Pbf  = (unsigned short*)(ws);              // 33554432 B
    unsigned short* Wbf  = (unsigned short*)(ws + 33554432);   //    65536 B
    float* qraw          = (float*)(ws + 33619968);            //  4194304 B
    float* kraw          = (float*)(ws + 37814272);            //  1048576 B
    float* vraw          = (float*)(ws + 38862848);            //  2097152 B
    float* qbn           = (float*)(ws + 40960000);            //  4194304 B
    unsigned short* vbn  = (unsigned short*)(ws + 45154304);   //  1048576 B
    float* scaleArr      = (float*)(ws + 46202880);            //      512 B
    float* shiftArr      = (float*)(ws + 46203392);            //      512 B
    float* lamc          = (float*)(ws + 46203904);            //    32768 B

    k_transp<<<dim3(1040), dim3(256), 0, stream>>>(pos, (unsigned*)Pbf, wq, wk, wv, (unsigned*)Wbf);
    k_proj<<<dim3(8, 16), dim3(256), 0, stream>>>(x, Wbf, qraw, kraw, vraw);
    k_stats<<<dim3(96), dim3(1024), 0, stream>>>(qraw, vraw, gq, bq, gv, bv, scaleArr, shiftArr);
    k_bn<<<dim3(512), dim3(256), 0, stream>>>(qraw, vraw, scaleArr, shiftArr, qbn, (unsigned*)vbn);
    k_sm_lamc<<<dim3(16, 16), dim3(256), 0, stream>>>(kraw, vbn, lamc);
    k_lamp<<<dim3(128, 4), dim3(256), 0, stream>>>(Pbf, vbn, qbn, lamc, out);
}

// Round 3
// 188.677 us; speedup vs baseline: 1.2553x; 1.0518x over previous
//
#include <hip/hip_runtime.h>
#include <hip/hip_bf16.h>
#include <cstdint>

// LambdaLayer on MI355X. b=16, dim=256, n=m=1024, HEADS=4, DIM_K=16, DIM_V=32.
// Pipeline (6 launches):
//   k_transp  : pos[n][m][k] fp32 -> Pbf[(n*16+k)][m] bf16 (LDS transpose, coalesced)
//               + blocks 1024..1039: w_q/w_k/w_v -> Wbf[128][256] bf16
//   k_proj    : per (b, px-tile 64): MFMA GEMM -> q_raw/k_raw/v_raw fp32
//   k_stats   : per-channel mean/var over (b,n) -> scale/shift (96 ch)
//   k_bn      : BN(q)+transpose -> qbn[b][n][64] fp32 ; BN(v) -> vbn[(b*32+v)][m] bf16
//   k_sm_lamc : softmax(k) over m + lam_c[b][16][32]
//   k_lamp    : GEMM lam_p = Pbf(16384x1024) @ vbn^T(1024x512), single-buffer BK=64,
//               LDS 33.8KB (4 blocks/CU), bf16 Y epilogue, fused out = q*(lamp+lamc)

typedef __attribute__((ext_vector_type(8))) __bf16 bf16x8;
typedef __attribute__((ext_vector_type(4))) float f32x4;

__device__ __forceinline__ unsigned short f2bf(float f) {
    unsigned u = __float_as_uint(f);
    u += 0x7fffu + ((u >> 16) & 1u);   // round-to-nearest-even
    return (unsigned short)(u >> 16);
}
__device__ __forceinline__ float bf2f(unsigned short h) {
    return __uint_as_float(((unsigned)h) << 16);
}
__device__ __forceinline__ void async16(const void* g, void* l) {
    __builtin_amdgcn_global_load_lds(
        (const __attribute__((address_space(1))) void*)g,
        (__attribute__((address_space(3))) void*)l, 16, 0, 0);
}

// ---------------------------------------------------------------- k_transp (+convw)
__global__ __launch_bounds__(256) void k_transp(const float* __restrict__ pos,
                                                unsigned* __restrict__ PbfU,
                                                const float* __restrict__ wq,
                                                const float* __restrict__ wk,
                                                const float* __restrict__ wv,
                                                unsigned* __restrict__ WbfU) {
    int blk = blockIdx.x;
    int t = threadIdx.x;
    if (blk >= 1024) {                    // weight conversion (16 blocks)
        int tt = (blk - 1024) * 256 + t;  // 0..4095
#pragma unroll
        for (int r = 0; r < 4; ++r) {
            int u = r * 4096 + tt;        // uint idx, 128x128
            int row = u >> 7;
            int cp = (u & 127) << 1;
            float f0 = 0.f, f1 = 0.f;
            if (row < 64)       { f0 = wq[row * 256 + cp];        f1 = wq[row * 256 + cp + 1]; }
            else if (row < 80)  { f0 = wk[(row - 64) * 256 + cp]; f1 = wk[(row - 64) * 256 + cp + 1]; }
            else if (row < 112) { f0 = wv[(row - 80) * 256 + cp]; f1 = wv[(row - 80) * 256 + cp + 1]; }
            WbfU[u] = (unsigned)f2bf(f0) | ((unsigned)f2bf(f1) << 16);
        }
        return;
    }
    __shared__ __align__(16) unsigned short L[16 * 1032];
    const float4* src = (const float4*)(pos + (size_t)blk * 16384);
#pragma unroll
    for (int r = 0; r < 16; ++r) {
        int idx4 = r * 256 + t;           // 0..4095 float4s
        float4 f = src[idx4];
        int m = idx4 >> 2, k0 = (idx4 & 3) << 2;
        L[(k0 + 0) * 1032 + m] = f2bf(f.x);
        L[(k0 + 1) * 1032 + m] = f2bf(f.y);
        L[(k0 + 2) * 1032 + m] = f2bf(f.z);
        L[(k0 + 3) * 1032 + m] = f2bf(f.w);
    }
    __syncthreads();
    uint2* dst = (uint2*)(PbfU + (size_t)blk * 8192);
#pragma unroll
    for (int r = 0; r < 16; ++r) {
        int c = r * 256 + t;              // uint2 chunk 0..4095
        int k = c >> 8, mo = c & 255;     // m0 = mo*4
        dst[c] = *(const uint2*)&L[k * 1032 + mo * 4];
    }
}

// ---------------------------------------------------------------- k_proj
// grid (16,16): 256 blocks. Block = 128 ch x 64 px, K=256 in 8 steps of 32.
__global__ __launch_bounds__(256) void k_proj(const float* __restrict__ x,
                                              const unsigned short* __restrict__ Wbf,
                                              float* __restrict__ qraw,
                                              float* __restrict__ kraw,
                                              float* __restrict__ vraw) {
    int b = blockIdx.y;
    int px0 = blockIdx.x * 64;
    int t = threadIdx.x;
    int w = t >> 6, lane = t & 63;

    __shared__ __align__(16) unsigned short Al[128 * 32];   // weights, swizzled octets
    __shared__ __align__(16) unsigned short Bl[64 * 34];    // [px][c], stride 34 (conflict-free)

    int srow = (w << 5) + (lane >> 2);
    int schunk = (lane & 3) ^ ((lane >> 3) & 3);
    const unsigned short* pA0 = Wbf + srow * 256 + schunk * 8;
    const unsigned short* pA1 = pA0 + 16 * 256;
    unsigned short* lA0 = &Al[w * 1024];
    unsigned short* lA1 = lA0 + 512;

    int wm = w >> 1, wn = w & 1;
    int rl = lane & 15, qq = lane >> 4;
    int sw = qq ^ ((rl >> 1) & 3);

    f32x4 acc[4][2];
#pragma unroll
    for (int i = 0; i < 4; ++i)
#pragma unroll
        for (int j = 0; j < 2; ++j)
#pragma unroll
            for (int r = 0; r < 4; ++r) acc[i][j][r] = 0.f;

    const float* xb = x + (size_t)b * 256 * 1024 + px0;

    for (int kt = 0; kt < 8; ++kt) {
        int c0 = kt * 32;
        async16(pA0 + c0, lA0);
        async16(pA1 + c0, lA1);
        // x -> Bl: 64 px x 32 c, pack 2 c per dword; wave lanes cover px 0..63
#pragma unroll
        for (int rep = 0; rep < 4; ++rep) {
            int idx = rep * 256 + t;
            int px = idx & 63;
            int cp = idx >> 6;                     // 0..15
            int c = c0 + cp * 2;
            float f0 = xb[(size_t)c * 1024 + px];
            float f1 = xb[(size_t)(c + 1) * 1024 + px];
            *(unsigned*)&Bl[px * 34 + cp * 2] = (unsigned)f2bf(f0) | ((unsigned)f2bf(f1) << 16);
        }
        __syncthreads();
        bf16x8 a[4], bb[2];
#pragma unroll
        for (int i = 0; i < 4; ++i) a[i]  = *(const bf16x8*)&Al[((wm << 6) + (i << 4) + rl) * 32 + sw * 8];
#pragma unroll
        for (int j = 0; j < 2; ++j) bb[j] = *(const bf16x8*)&Bl[((wn << 5) + (j << 4) + rl) * 34 + qq * 8];
#pragma unroll
        for (int i = 0; i < 4; ++i)
#pragma unroll
            for (int j = 0; j < 2; ++j)
                acc[i][j] = __builtin_amdgcn_mfma_f32_16x16x32_bf16(a[i], bb[j], acc[i][j], 0, 0, 0);
        __syncthreads();
    }

#pragma unroll
    for (int i = 0; i < 4; ++i) {
#pragma unroll
        for (int j = 0; j < 2; ++j) {
            int px = px0 + (wn << 5) + (j << 4) + (lane & 15);
#pragma unroll
            for (int r = 0; r < 4; ++r) {
                int ch = (wm << 6) + (i << 4) + ((lane >> 4) << 2) + r;
                float val = acc[i][j][r];
                if (ch < 64)       qraw[((size_t)b * 64 + ch) * 1024 + px] = val;
                else if (ch < 80)  kraw[((size_t)b * 16 + (ch - 64)) * 1024 + px] = val;
                else if (ch < 112) vraw[((size_t)b * 32 + (ch - 80)) * 1024 + px] = val;
            }
        }
    }
}

// ---------------------------------------------------------------- k_stats
__global__ __launch_bounds__(1024) void k_stats(const float* __restrict__ qraw,
                                                const float* __restrict__ vraw,
                                                const float* __restrict__ gq, const float* __restrict__ bq,
                                                const float* __restrict__ gv, const float* __restrict__ bv,
                                                float* __restrict__ scaleArr, float* __restrict__ shiftArr) {
    int ch = blockIdx.x;   // 0..95
    int t = threadIdx.x;   // 0..1023
    const float* base;
    size_t bstride;
    if (ch < 64) { base = qraw + (size_t)ch * 1024; bstride = 64 * 1024; }
    else         { base = vraw + (size_t)(ch - 64) * 1024; bstride = 32 * 1024; }
    float s = 0.f, ss = 0.f;
#pragma unroll
    for (int b = 0; b < 16; ++b) { float v = base[b * bstride + t]; s += v; ss += v * v; }
#pragma unroll
    for (int off = 32; off; off >>= 1) { s += __shfl_down(s, off); ss += __shfl_down(ss, off); }
    __shared__ float rs[16], rss[16];
    if ((t & 63) == 0) { rs[t >> 6] = s; rss[t >> 6] = ss; }
    __syncthreads();
    if (t == 0) {
        s = 0.f; ss = 0.f;
#pragma unroll
        for (int i = 0; i < 16; ++i) { s += rs[i]; ss += rss[i]; }
        float mean = s * (1.f / 16384.f);
        float var = ss * (1.f / 16384.f) - mean * mean;
        float g, be;
        if (ch < 64) { g = gq[ch]; be = bq[ch]; } else { g = gv[ch - 64]; be = bv[ch - 64]; }
        float sc = g * rsqrtf(var + 1e-5f);
        scaleArr[ch] = sc;
        shiftArr[ch] = be - mean * sc;
    }
}

// ---------------------------------------------------------------- k_bn
__global__ void k_bn(const float* __restrict__ qraw, const float* __restrict__ vraw,
                     const float* __restrict__ scaleArr, const float* __restrict__ shiftArr,
                     float* __restrict__ qbn, unsigned* __restrict__ vbnU) {
    int bx = blockIdx.x;
    int t = threadIdx.x;
    if (bx < 256) {   // BN(q) + transpose
        int nt = bx & 15, b = bx >> 4;
        __shared__ float Q[64 * 65];
        const float* src = qraw + (size_t)b * 64 * 1024 + nt * 64;
#pragma unroll
        for (int r = 0; r < 16; ++r) {
            int idx = r * 256 + t; int ch = idx >> 6; int nl = idx & 63;
            Q[ch * 65 + nl] = src[(size_t)ch * 1024 + nl];
        }
        __syncthreads();
        float* dst = qbn + ((size_t)b * 1024 + nt * 64) * 64;
#pragma unroll
        for (int r = 0; r < 16; ++r) {
            int idx = r * 256 + t; int nl = idx >> 6; int ch = idx & 63;
            dst[(size_t)nl * 64 + ch] = Q[ch * 65 + nl] * scaleArr[ch] + shiftArr[ch];
        }
    } else {          // BN(v) -> bf16
        int tt = (bx - 256) * 256 + t;
#pragma unroll
        for (int r = 0; r < 4; ++r) {
            int u = r * 65536 + tt;           // uint idx 0..262143
            int row = u >> 9;
            int vch = row & 31;
            float sc = scaleArr[64 + vch], sh = shiftArr[64 + vch];
            float f0 = vraw[2 * u] * sc + sh;
            float f1 = vraw[2 * u + 1] * sc + sh;
            vbnU[u] = (unsigned)f2bf(f0) | ((unsigned)f2bf(f1) << 16);
        }
    }
}

// ---------------------------------------------------------------- k_sm_lamc
__global__ void k_sm_lamc(const float* __restrict__ kraw, const unsigned short* __restrict__ vbn,
                          float* __restrict__ lamc) {
    int kch = blockIdx.x, b = blockIdx.y;
    int t = threadIdx.x; int w = t >> 6; int lane = t & 63;
    const float* kr = kraw + ((size_t)b * 16 + kch) * 1024;
    float xv[4];
    float mx = -1e30f;
#pragma unroll
    for (int i = 0; i < 4; ++i) { xv[i] = kr[t + i * 256]; mx = fmaxf(mx, xv[i]); }
#pragma unroll
    for (int off = 32; off; off >>= 1) mx = fmaxf(mx, __shfl_down(mx, off));
    __shared__ float red[4];
    __shared__ float pr[4][32];
    if (lane == 0) red[w] = mx;
    __syncthreads();
    mx = fmaxf(fmaxf(red[0], red[1]), fmaxf(red[2], red[3]));
    float e[4]; float s = 0.f;
#pragma unroll
    for (int i = 0; i < 4; ++i) { e[i] = __expf(xv[i] - mx); s += e[i]; }
#pragma unroll
    for (int off = 32; off; off >>= 1) s += __shfl_down(s, off);
    __syncthreads();
    if (lane == 0) red[w] = s;
    __syncthreads();
    float inv = 1.f / (red[0] + red[1] + red[2] + red[3]);
    const unsigned short* vb = vbn + (size_t)b * 32 * 1024;
    for (int vch = 0; vch < 32; ++vch) {
        const unsigned short* vr = vb + (size_t)vch * 1024;
        float p = 0.f;
#pragma unroll
        for (int i = 0; i < 4; ++i) p += e[i] * bf2f(vr[t + i * 256]);
#pragma unroll
        for (int off = 32; off; off >>= 1) p += __shfl_down(p, off);
        if (lane == 0) pr[w][vch] = p;
    }
    __syncthreads();
    if (t < 32) {
        float tot = pr[0][t] + pr[1][t] + pr[2][t] + pr[3][t];
        lamc[((size_t)b * 16 + kch) * 32 + t] = inv * tot;
    }
}

// ---------------------------------------------------------------- k_lamp
// GEMM M=16384, N=512, K=1024. grid(128,4): ntile siblings share XCD (id%8).
// Single-buffer BK=64 (m97 structure), LDS 33.8KB -> 4 blocks/CU with VGPR<=128.
__global__ __launch_bounds__(256, 4) void k_lamp(const unsigned short* __restrict__ Pbf,
                                                 const unsigned short* __restrict__ vbn,
                                                 const float* __restrict__ qbn,
                                                 const float* __restrict__ lamc,
                                                 float* __restrict__ out) {
    int mtile = blockIdx.x;    // 0..127
    int ntile = blockIdx.y;    // 0..3
    int t = threadIdx.x;
    int w = t >> 6, lane = t & 63;

    __shared__ union {
        struct { __align__(16) unsigned short A[8192]; __align__(16) unsigned short B[8192]; } st; // 32KB
        unsigned short Ybf[128 * 132];   // 33792 B (pad 4 shorts/row)
    } sm;

    // staging: instr i covers rows i*32 + (t>>3); octet XOR-swizzled by row&7
    int srow = t >> 3;                    // 0..31
    int jx = (t & 7) ^ (srow & 7);
    const unsigned short* pA = Pbf + ((size_t)(mtile * 128) + srow) * 1024 + jx * 8;
    const unsigned short* pB = vbn + ((size_t)(ntile * 128) + srow) * 1024 + jx * 8;
    unsigned short* ldsA = &sm.st.A[t * 8];
    unsigned short* ldsB = &sm.st.B[t * 8];

    int wm = w >> 1, wn = w & 1;
    int rl = lane & 15, qq = lane >> 4;
    // row&7 == rl&7 for all i -> swizzle i-invariant; 2 bases per side
    int abase[2], bbase[2];
#pragma unroll
    for (int ks = 0; ks < 2; ++ks) {
        abase[ks] = (wm * 64 + rl) * 64 + (((ks * 4 + qq) ^ (rl & 7)) << 3);
        bbase[ks] = (wn * 64 + rl) * 64 + (((ks * 4 + qq) ^ (rl & 7)) << 3);
    }

    f32x4 acc[4][4];
#pragma unroll
    for (int i = 0; i < 4; ++i)
#pragma unroll
        for (int j = 0; j < 4; ++j)
#pragma unroll
            for (int r = 0; r < 4; ++r) acc[i][j][r] = 0.f;

    for (int kt = 0; kt < 16; ++kt) {
        int m0 = kt * 64;
#pragma unroll
        for (int i = 0; i < 4; ++i) {
            async16(pA + (size_t)i * 32 * 1024 + m0, ldsA + i * 2048);
            async16(pB + (size_t)i * 32 * 1024 + m0, ldsB + i * 2048);
        }
        __syncthreads();
#pragma unroll
        for (int ks = 0; ks < 2; ++ks) {
            bf16x8 a[4], bb[4];
#pragma unroll
            for (int i = 0; i < 4; ++i) a[i]  = *(const bf16x8*)&sm.st.A[abase[ks] + i * 1024];
#pragma unroll
            for (int j = 0; j < 4; ++j) bb[j] = *(const bf16x8*)&sm.st.B[bbase[ks] + j * 1024];
#pragma unroll
            for (int i = 0; i < 4; ++i)
#pragma unroll
                for (int j = 0; j < 4; ++j)
                    acc[i][j] = __builtin_amdgcn_mfma_f32_16x16x32_bf16(a[i], bb[j], acc[i][j], 0, 0, 0);
        }
        __syncthreads();
    }

    // acc + lam_c -> Ybf (bf16, stride 132); safe: all ds_reads drained by last barrier
    int b0 = ntile * 4;
#pragma unroll
    for (int i = 0; i < 4; ++i) {
        int row_b = (wm << 6) + (i << 4) + (qq << 2);
#pragma unroll
        for (int j = 0; j < 4; ++j) {
            int col = (wn << 6) + (j << 4) + rl;
            int bcol = col >> 5, vv = col & 31;
            const float* lc = lamc + ((size_t)(b0 + bcol) * 16) * 32 + vv;
#pragma unroll
            for (int r = 0; r < 4; ++r) {
                int row = row_b + r;
                sm.Ybf[row * 132 + col] = f2bf(acc[i][j][r] + lc[(row & 15) * 32]);
            }
        }
    }
    __syncthreads();

    // epilogue: thread owns (b, h, v0..v0+1), loops 8 n: out = sum_k q * lam
    int c0 = t * 2;
    int bb2 = c0 >> 7;
    int hh = (c0 >> 5) & 3;
    int v0 = c0 & 31;
    int bglob = b0 + bb2;
    float o0[8], o1[8];
#pragma unroll
    for (int nn = 0; nn < 8; ++nn) { o0[nn] = 0.f; o1[nn] = 0.f; }
    const float* qb = qbn + ((size_t)bglob * 1024 + mtile * 8) * 64 + hh * 16;
#pragma unroll
    for (int nn = 0; nn < 8; ++nn) {
        const float* qr = qb + nn * 64;
        float qv[16];
        *(float4*)&qv[0]  = *(const float4*)&qr[0];
        *(float4*)&qv[4]  = *(const float4*)&qr[4];
        *(float4*)&qv[8]  = *(const float4*)&qr[8];
        *(float4*)&qv[12] = *(const float4*)&qr[12];
        const unsigned short* yrow = &sm.Ybf[(nn * 16) * 132 + bb2 * 32 + v0];
#pragma unroll
        for (int k = 0; k < 16; ++k) {
            float y0 = bf2f(yrow[k * 132]);
            float y1 = bf2f(yrow[k * 132 + 1]);
            o0[nn] += qv[k] * y0;
            o1[nn] += qv[k] * y1;
        }
    }
    float* op = out + ((size_t)bglob * 128 + hh * 32 + v0) * 1024 + mtile * 8;
    ((float4*)op)[0] = make_float4(o0[0], o0[1], o0[2], o0[3]);
    ((float4*)op)[1] = make_float4(o0[4], o0[5], o0[6], o0[7]);
    float* op1 = op + 1024;
    ((float4*)op1)[0] = make_float4(o1[0], o1[1], o1[2], o1[3]);
    ((float4*)op1)[1] = make_float4(o1[4], o1[5], o1[6], o1[7]);
}

// ---------------------------------------------------------------- launch
extern "C" void kernel_launch(void* const* d_in, const int* in_sizes, int n_in,
                              void* d_out, int out_size, void* d_ws, size_t ws_size,
                              hipStream_t stream) {
    const float* x   = (const float*)d_in[0];
    const float* wq  = (const float*)d_in[1];
    const float* wk  = (const float*)d_in[2];
    const float* wv  = (const float*)d_in[3];
    const float* pos = (const float*)d_in[4];
    const float* gq  = (const float*)d_in[5];
    const float* bq  = (const float*)d_in[6];
    const float* gv  = (const float*)d_in[7];
    const float* bv  = (const float*)d_in[8];
    float* out = (float*)d_out;

    char* ws = (char*)d_ws;
    unsigned short* Pbf  = (unsigned short*)(ws);              // 33554432 B
    unsigned short* Wbf  = (unsigned short*)(ws + 33554432);   //    65536 B
    float* qraw          = (float*)(ws + 33619968);            //  4194304 B
    float* kraw          = (float*)(ws + 37814272);            //  1048576 B
    float* vraw          = (float*)(ws + 38862848);            //  2097152 B
    float* qbn           = (float*)(ws + 40960000);            //  4194304 B
    unsigned short* vbn  = (unsigned short*)(ws + 45154304);   //  1048576 B
    float* scaleArr      = (float*)(ws + 46202880);            //      512 B
    float* shiftArr      = (float*)(ws + 46203392);            //      512 B
    float* lamc          = (float*)(ws + 46203904);            //    32768 B

    k_transp<<<dim3(1040), dim3(256), 0, stream>>>(pos, (unsigned*)Pbf, wq, wk, wv, (unsigned*)Wbf);
    k_proj<<<dim3(16, 16), dim3(256), 0, stream>>>(x, Wbf, qraw, kraw, vraw);
    k_stats<<<dim3(96), dim3(1024), 0, stream>>>(qraw, vraw, gq, bq, gv, bv, scaleArr, shiftArr);
    k_bn<<<dim3(512), dim3(256), 0, stream>>>(qraw, vraw, scaleArr, shiftArr, qbn, (unsigned*)vbn);
    k_sm_lamc<<<dim3(16, 16), dim3(256), 0, stream>>>(kraw, vbn, lamc);
    k_lamp<<<dim3(128, 4), dim3(256), 0, stream>>>(Pbf, vbn, qbn, lamc, out);
}